// Round 5
// baseline (2296.766 us; speedup 1.0000x reference)
//
#include <hip/hip_runtime.h>
#include <stdint.h>

typedef unsigned long long u64;
typedef unsigned int u32;

#define NB 32     // batches
#define NP 8192   // points per batch
#define NG 256    // FPS centers
#define NK 32     // neighbors per center
#define NTASK (NB * NG)           // 8192 knn tasks
#define KNN_BLOCKS (NTASK / 8)    // 8 waves (tasks) per 512-thread block

// d_ws layout: u32 flags[8192] | u32 cx[8192] | u32 cy[8192] | u32 cz[8192]
// slot index s = b*NG + g. flag==1 => coords valid (release/acquire, agent scope).

// Exact IEEE ops (block FMA contraction so we bit-match the numpy reference):
// d = ((dx*dx) + (dy*dy)) + (dz*dz)
__device__ __forceinline__ float dist3(float dx, float dy, float dz) {
    return __fadd_rn(__fadd_rn(__fmul_rn(dx, dx), __fmul_rn(dy, dy)), __fmul_rn(dz, dz));
}

// ---- DPP wave reductions (VALU-only, no LDS pipe) ----------------------------
#define DPP_STEP(v, ctrl, rmask) __builtin_amdgcn_update_dpp((int)(v), (int)(v), (ctrl), (rmask), 0xf, false)

__device__ __forceinline__ u32 wave_max_u32(u32 v) {
    u32 o;
    o = (u32)DPP_STEP(v, 0x111, 0xf); v = (o > v) ? o : v;  // row_shr:1
    o = (u32)DPP_STEP(v, 0x112, 0xf); v = (o > v) ? o : v;  // row_shr:2
    o = (u32)DPP_STEP(v, 0x114, 0xf); v = (o > v) ? o : v;  // row_shr:4
    o = (u32)DPP_STEP(v, 0x118, 0xf); v = (o > v) ? o : v;  // row_shr:8
    o = (u32)DPP_STEP(v, 0x142, 0xa); v = (o > v) ? o : v;  // row_bcast:15
    o = (u32)DPP_STEP(v, 0x143, 0xc); v = (o > v) ? o : v;  // row_bcast:31
    return (u32)__builtin_amdgcn_readlane((int)v, 63);
}

__device__ __forceinline__ u32 wave_min_u32(u32 v) {
    u32 o;
    o = (u32)DPP_STEP(v, 0x111, 0xf); v = (o < v) ? o : v;
    o = (u32)DPP_STEP(v, 0x112, 0xf); v = (o < v) ? o : v;
    o = (u32)DPP_STEP(v, 0x114, 0xf); v = (o < v) ? o : v;
    o = (u32)DPP_STEP(v, 0x118, 0xf); v = (o < v) ? o : v;
    o = (u32)DPP_STEP(v, 0x142, 0xa); v = (o < v) ? o : v;
    o = (u32)DPP_STEP(v, 0x143, 0xc); v = (o < v) ? o : v;
    return (u32)__builtin_amdgcn_readlane((int)v, 63);
}

// ---------------------------------------------------------------------------
// init: zero the per-center ready flags (d_ws is NOT re-poisoned between
// graph replays, so this must run every kernel_launch call).
// ---------------------------------------------------------------------------
__global__ void init_kernel(u32* __restrict__ ws)
{
    int i = blockIdx.x * 256 + threadIdx.x;
    if (i < NTASK) ws[i] = 0;
}

// ---------------------------------------------------------------------------
// FPS role (blocks 0..31): one block (512 threads, 8 waves) per batch; 16
// points per thread, pinned live via empty asm. One pass + block argmax per
// iteration. Centroid broadcast via LDS (owner writes, 2nd barrier) instead
// of a dependent L2 re-fetch. Owner publishes each center to the slot array
// (relaxed coord stores + release flag, agent scope) for the knn waves.
// Bit-exact vs reference: dist = min(dist, ((dx*dx)+(dy*dy))+(dz*dz));
// argmax = first index of max (ties -> larger NP-1-idx = smaller idx).
// ---------------------------------------------------------------------------
__device__ void fps_role(const float* __restrict__ xyz, float* __restrict__ out,
                         u32* __restrict__ ws)
{
    const int b = blockIdx.x;
    const int t = threadIdx.x;
    const int wid = t >> 6, lane = t & 63;

    __shared__ u64 wavekey[2][8];
    __shared__ float cb[3];

    u32* flags = ws;
    u32* cxa = ws + NTASK;
    u32* cya = ws + 2 * NTASK;
    u32* cza = ws + 3 * NTASK;

    const float* base = xyz + (size_t)b * NP * 3;

    float px[16], py[16], pz[16], dist[16];
    {
        const float4* src = reinterpret_cast<const float4*>(base) + t * 12;
        float4 f[12];
        #pragma unroll
        for (int i = 0; i < 12; ++i) f[i] = src[i];
        float fl[48];
        #pragma unroll
        for (int i = 0; i < 12; ++i) {
            fl[4*i] = f[i].x; fl[4*i+1] = f[i].y; fl[4*i+2] = f[i].z; fl[4*i+3] = f[i].w;
        }
        #pragma unroll
        for (int j = 0; j < 16; ++j) {
            px[j] = fl[3*j]; py[j] = fl[3*j+1]; pz[j] = fl[3*j+2];
            dist[j] = 1e10f;
        }
    }
    // Liveness pin: block rematerialization of the loads.
    #pragma unroll
    for (int j = 0; j < 16; ++j) {
        asm volatile("" : "+v"(px[j]), "+v"(py[j]), "+v"(pz[j]));
    }

    // first centroid = point 0; publish slot (b,0)
    float cx, cy, cz;
    {
        float4 f0 = *reinterpret_cast<const float4*>(base);
        cx = f0.x; cy = f0.y; cz = f0.z;
        if (t == 0) {
            float* o = out + (size_t)b * NG * 3;
            o[0] = cx; o[1] = cy; o[2] = cz;
            int s = b * NG;
            __hip_atomic_store(&cxa[s], __float_as_uint(cx), __ATOMIC_RELAXED, __HIP_MEMORY_SCOPE_AGENT);
            __hip_atomic_store(&cya[s], __float_as_uint(cy), __ATOMIC_RELAXED, __HIP_MEMORY_SCOPE_AGENT);
            __hip_atomic_store(&cza[s], __float_as_uint(cz), __ATOMIC_RELAXED, __HIP_MEMORY_SCOPE_AGENT);
            __hip_atomic_store(&flags[s], 1u, __ATOMIC_RELEASE, __HIP_MEMORY_SCOPE_AGENT);
        }
    }

    for (int g = 0; g < NG - 1; ++g) {
        #pragma unroll
        for (int j = 0; j < 16; ++j) {
            float dx = __fsub_rn(px[j], cx);
            float dy = __fsub_rn(py[j], cy);
            float dz = __fsub_rn(pz[j], cz);
            float d  = dist3(dx, dy, dz);
            dist[j] = fminf(dist[j], d);
        }
        // tree max over the 16 updated dists (max3-friendly)
        float m0 = fmaxf(fmaxf(dist[0],  dist[1]),  dist[2]);
        float m1 = fmaxf(fmaxf(dist[3],  dist[4]),  dist[5]);
        float m2 = fmaxf(fmaxf(dist[6],  dist[7]),  dist[8]);
        float m3 = fmaxf(fmaxf(dist[9],  dist[10]), dist[11]);
        float m4 = fmaxf(fmaxf(dist[12], dist[13]), dist[14]);
        float m5 = fmaxf(fmaxf(m0, m1), m2);
        float m6 = fmaxf(fmaxf(m3, m4), dist[15]);
        float bestd = fmaxf(m5, m6);

        u32 hi = __float_as_uint(bestd);      // dist >= 0 -> bits order-monotone
        u32 mh = wave_max_u32(hi);
        u32 cl = 0;
        if (hi == mh) {
            // recover FIRST local index of the max (>=1 lane per wave runs this)
            u32 bestj = 0;
            #pragma unroll
            for (int j = 15; j >= 0; --j)
                if (dist[j] == bestd) bestj = (u32)j;
            cl = (u32)(NP - 1 - (t * 16 + (int)bestj));   // larger = smaller idx
        }
        u32 ml = wave_max_u32(cl);
        if (lane == 0) wavekey[g & 1][wid] = ((u64)mh << 32) | (u64)ml;
        __syncthreads();

        u64 wk = wavekey[g & 1][0];
        #pragma unroll
        for (int w = 1; w < 8; ++w) {
            u64 o = wavekey[g & 1][w];
            wk = (o > wk) ? o : wk;
        }
        const int widx = NP - 1 - (int)(u32)(wk & 0xFFFFFFFFull);
        if ((widx >> 4) == t) {
            const int j = widx & 15;
            cb[0] = px[j]; cb[1] = py[j]; cb[2] = pz[j];
            float* o = out + ((size_t)b * NG + g + 1) * 3;
            o[0] = px[j]; o[1] = py[j]; o[2] = pz[j];
            int s = b * NG + g + 1;
            __hip_atomic_store(&cxa[s], __float_as_uint(px[j]), __ATOMIC_RELAXED, __HIP_MEMORY_SCOPE_AGENT);
            __hip_atomic_store(&cya[s], __float_as_uint(py[j]), __ATOMIC_RELAXED, __HIP_MEMORY_SCOPE_AGENT);
            __hip_atomic_store(&cza[s], __float_as_uint(pz[j]), __ATOMIC_RELAXED, __HIP_MEMORY_SCOPE_AGENT);
            __hip_atomic_store(&flags[s], 1u, __ATOMIC_RELEASE, __HIP_MEMORY_SCOPE_AGENT);
        }
        __syncthreads();
        cx = cb[0]; cy = cb[1]; cz = cb[2];
    }
}

// ---------------------------------------------------------------------------
// knn role: one WAVE per task (b,g). Spins (agent-scope acquire) on the
// center's ready flag, then streams 128 points/lane keeping the 4 smallest
// packed keys; 32 DPP-min extraction rounds (ballot+ffs tie-break to the
// lowest lane = smallest index). Exact lazy rescan if a lane empties.
// ---------------------------------------------------------------------------
__device__ __forceinline__ void build_top4(const float4* __restrict__ src,
                                           float cx, float cy, float cz, float s2,
                                           u64 L, bool useL, int lane,
                                           u64& t0, u64& t1, u64& t2, u64& t3)
{
    t0 = t1 = t2 = t3 = ~0ull;
    #pragma unroll 4
    for (int q = 0; q < 32; ++q) {
        float4 f0 = src[q*3+0];
        float4 f1 = src[q*3+1];
        float4 f2 = src[q*3+2];
        float a[12] = {f0.x,f0.y,f0.z,f0.w, f1.x,f1.y,f1.z,f1.w, f2.x,f2.y,f2.z,f2.w};
        #pragma unroll
        for (int rr = 0; rr < 4; ++rr) {
            float nx = a[rr*3+0], ny = a[rr*3+1], nz = a[rr*3+2];
            // reference: (||s||^2 - 2*(s.n)) + ||n||^2, left-to-right, no FMA
            float dotv = __fadd_rn(__fadd_rn(__fmul_rn(cx,nx), __fmul_rn(cy,ny)), __fmul_rn(cz,nz));
            float n2   = dist3(nx, ny, nz);
            float d    = __fadd_rn(__fsub_rn(s2, __fmul_rn(2.0f, dotv)), n2);
            // monotone map f32 -> u32 (handles the tiny-negative self-distance)
            u32 u  = __float_as_uint(d);
            u32 kk = u ^ (u32)(((int)u >> 31) | 0x80000000);
            int idx = lane * 128 + q * 4 + rr;
            u64 pk = ((u64)kk << 32) | (u64)(u32)idx;
            if (!useL || pk > L) {
                if (pk < t3) {
                    t3 = pk;
                    if (t3 < t2) { u64 tmp = t2; t2 = t3; t3 = tmp; }
                    if (t2 < t1) { u64 tmp = t1; t1 = t2; t2 = tmp; }
                    if (t1 < t0) { u64 tmp = t0; t0 = t1; t1 = tmp; }
                }
            }
        }
    }
}

__device__ void knn_role(const float* __restrict__ xyz, float* __restrict__ out,
                         u32* __restrict__ ws)
{
    const int t    = threadIdx.x;
    const int lane = t & 63;
    const int wid  = t >> 6;
    const int task = (blockIdx.x - NB) * 8 + wid;  // g-major: ready-earliest first
    const int g    = task >> 5;                    // 0..255
    const int b    = task & 31;                    // 0..31

    u32* flags = ws;
    u32* cxa = ws + NTASK;
    u32* cya = ws + 2 * NTASK;
    u32* cza = ws + 3 * NTASK;
    const int s = b * NG + g;

    // wait for center (b,g)
    while (__hip_atomic_load(&flags[s], __ATOMIC_ACQUIRE, __HIP_MEMORY_SCOPE_AGENT) == 0u) {
        __builtin_amdgcn_s_sleep(2);
    }
    const float cx = __uint_as_float(__hip_atomic_load(&cxa[s], __ATOMIC_RELAXED, __HIP_MEMORY_SCOPE_AGENT));
    const float cy = __uint_as_float(__hip_atomic_load(&cya[s], __ATOMIC_RELAXED, __HIP_MEMORY_SCOPE_AGENT));
    const float cz = __uint_as_float(__hip_atomic_load(&cza[s], __ATOMIC_RELAXED, __HIP_MEMORY_SCOPE_AGENT));
    const float s2 = dist3(cx, cy, cz);

    const float4* src = reinterpret_cast<const float4*>(xyz + (size_t)b * NP * 3) + (size_t)lane * 96;

    u64 t0, t1, t2, t3;
    build_top4(src, cx, cy, cz, s2, 0ull, false, lane, t0, t1, t2, t3);
    int cnt = 4;
    u64 L = 0;
    u32 myWin = 0;

    for (int round = 0; round < NK; ++round) {
        if (cnt == 0) {
            build_top4(src, cx, cy, cz, s2, L, true, lane, t0, t1, t2, t3);
            cnt = 4;
        }
        u32 hi0 = (u32)(t0 >> 32);
        u32 lo0 = (u32)(t0 & 0xFFFFFFFFull);
        u32 mh = wave_min_u32(hi0);
        u64 bmask = __ballot(hi0 == mh);
        int owner = __ffsll((unsigned long long)bmask) - 1;  // lowest lane = smallest idx
        u32 widx = (u32)__builtin_amdgcn_readlane((int)lo0, owner);
        if (lane == owner) {
            L = t0;
            t0 = t1; t1 = t2; t2 = t3; t3 = ~0ull;
            --cnt;
        }
        if (lane == round) myWin = widx;
    }

    float sx = 0.f, sy = 0.f, sz = 0.f;
    if (lane < NK) {
        const float* p = xyz + ((size_t)b * NP + myWin) * 3;
        sx = p[0]; sy = p[1]; sz = p[2];
    }
    #pragma unroll
    for (int m = 32; m >= 1; m >>= 1) {
        sx += __shfl_xor(sx, m, 64);
        sy += __shfl_xor(sy, m, 64);
        sz += __shfl_xor(sz, m, 64);
    }
    if (lane == 0) {
        float* o = out + (size_t)NB * NG * 3 + ((size_t)b * NG + g) * 3;
        const float inv = 1.0f / 32.0f;   // /32 exact (power of 2)
        o[0] = sx * inv; o[1] = sy * inv; o[2] = sz * inv;
    }
}

__global__ __launch_bounds__(512, 2) void fused_kernel(const float* __restrict__ xyz,
                                                       float* __restrict__ out,
                                                       u32* __restrict__ ws)
{
    if (blockIdx.x < NB) fps_role(xyz, out, ws);
    else                 knn_role(xyz, out, ws);
}

extern "C" void kernel_launch(void* const* d_in, const int* in_sizes, int n_in,
                              void* d_out, int out_size, void* d_ws, size_t ws_size,
                              hipStream_t stream)
{
    const float* xyz = (const float*)d_in[0];
    float* out = (float*)d_out;
    u32* ws = (u32*)d_ws;

    hipLaunchKernelGGL(init_kernel, dim3(NTASK / 256), dim3(256), 0, stream, ws);
    hipLaunchKernelGGL(fused_kernel, dim3(NB + KNN_BLOCKS), dim3(512), 0, stream, xyz, out, ws);
}

// Round 7
// 378.271 us; speedup vs baseline: 6.0717x; 6.0717x over previous
//
#include <hip/hip_runtime.h>
#include <stdint.h>

typedef unsigned long long u64;
typedef unsigned int u32;
typedef float v2f __attribute__((ext_vector_type(2)));

#define NB 32     // batches
#define NP 8192   // points per batch
#define NG 256    // FPS centers
#define NK 32     // neighbors per center

// Exact IEEE ops (block FMA contraction so we bit-match the numpy reference):
// d = ((dx*dx) + (dy*dy)) + (dz*dz)
__device__ __forceinline__ float dist3(float dx, float dy, float dz) {
    return __fadd_rn(__fadd_rn(__fmul_rn(dx, dx), __fmul_rn(dy, dy)), __fmul_rn(dz, dz));
}

// ---- DPP wave reductions (VALU-only, no LDS pipe) ----------------------------
#define DPP_STEP(v, ctrl, rmask) __builtin_amdgcn_update_dpp((int)(v), (int)(v), (ctrl), (rmask), 0xf, false)

__device__ __forceinline__ u32 wave_max_u32(u32 v) {
    u32 o;
    o = (u32)DPP_STEP(v, 0x111, 0xf); v = (o > v) ? o : v;  // row_shr:1
    o = (u32)DPP_STEP(v, 0x112, 0xf); v = (o > v) ? o : v;  // row_shr:2
    o = (u32)DPP_STEP(v, 0x114, 0xf); v = (o > v) ? o : v;  // row_shr:4
    o = (u32)DPP_STEP(v, 0x118, 0xf); v = (o > v) ? o : v;  // row_shr:8
    o = (u32)DPP_STEP(v, 0x142, 0xa); v = (o > v) ? o : v;  // row_bcast:15
    o = (u32)DPP_STEP(v, 0x143, 0xc); v = (o > v) ? o : v;  // row_bcast:31
    return (u32)__builtin_amdgcn_readlane((int)v, 63);
}

__device__ __forceinline__ u32 wave_min_u32(u32 v) {
    u32 o;
    o = (u32)DPP_STEP(v, 0x111, 0xf); v = (o < v) ? o : v;
    o = (u32)DPP_STEP(v, 0x112, 0xf); v = (o < v) ? o : v;
    o = (u32)DPP_STEP(v, 0x114, 0xf); v = (o < v) ? o : v;
    o = (u32)DPP_STEP(v, 0x118, 0xf); v = (o < v) ? o : v;
    o = (u32)DPP_STEP(v, 0x142, 0xa); v = (o < v) ? o : v;
    o = (u32)DPP_STEP(v, 0x143, 0xc); v = (o < v) ? o : v;
    return (u32)__builtin_amdgcn_readlane((int)v, 63);
}

// ---------------------------------------------------------------------------
// Kernel 1: farthest point sampling (round-2 structure + packed-f32 distance
// update; VERIFIED bit-exact in round 6 — output 0 passed). One block (512
// threads, 8 waves) per batch; 16 points per thread held as 8 float2-pairs.
// One barrier per iteration (parity-double-buffered wavekey); next centroid
// re-fetched by all lanes via a same-address (broadcast, L2-hot) load.
// fp contract(off) keeps packed mul/add unfused -> per-element ops bit-match
// the reference: dist = min(dist, ((dx*dx)+(dy*dy))+(dz*dz));
// argmax = first index of max (ties -> larger NP-1-idx = smaller idx).
// ---------------------------------------------------------------------------
__global__ __launch_bounds__(512, 2) void fps_kernel(const float* __restrict__ xyz,
                                                     float* __restrict__ out)
{
    #pragma clang fp contract(off)
    const int b = blockIdx.x;
    const int t = threadIdx.x;
    const int wid = t >> 6, lane = t & 63;

    __shared__ u64 wavekey[2][8];

    const float* base = xyz + (size_t)b * NP * 3;

    v2f px[8], py[8], pz[8], dist[8];
    {
        const float4* src = reinterpret_cast<const float4*>(base) + t * 12;
        float4 f[12];
        #pragma unroll
        for (int i = 0; i < 12; ++i) f[i] = src[i];
        float fl[48];
        #pragma unroll
        for (int i = 0; i < 12; ++i) {
            fl[4*i] = f[i].x; fl[4*i+1] = f[i].y; fl[4*i+2] = f[i].z; fl[4*i+3] = f[i].w;
        }
        #pragma unroll
        for (int j = 0; j < 8; ++j) {
            px[j] = (v2f){fl[6*j+0], fl[6*j+3]};
            py[j] = (v2f){fl[6*j+1], fl[6*j+4]};
            pz[j] = (v2f){fl[6*j+2], fl[6*j+5]};
            dist[j] = (v2f){1e10f, 1e10f};
        }
    }

    // first centroid = point 0
    float cx, cy, cz;
    {
        float4 f0 = *reinterpret_cast<const float4*>(base);
        cx = f0.x; cy = f0.y; cz = f0.z;
        if (t == 0) {
            float* o = out + (size_t)b * NG * 3;
            o[0] = cx; o[1] = cy; o[2] = cz;
        }
    }

    for (int g = 0; g < NG - 1; ++g) {
        const v2f cvx = (v2f){cx, cx};
        const v2f cvy = (v2f){cy, cy};
        const v2f cvz = (v2f){cz, cz};
        float bestd = -1.0f;
        u32 bestj = 0;
        #pragma unroll
        for (int j = 0; j < 8; ++j) {
            v2f dx = px[j] - cvx;
            v2f dy = py[j] - cvy;
            v2f dz = pz[j] - cvz;
            v2f qx = dx * dx;
            v2f qy = dy * dy;
            v2f qz = dz * dz;
            v2f s  = (qx + qy) + qz;
            float d0 = fminf(dist[j].x, s.x);
            float d1 = fminf(dist[j].y, s.y);
            dist[j].x = d0;
            dist[j].y = d1;
            bool g0 = d0 > bestd;               // strict >, ascending order => first max
            bestd = g0 ? d0 : bestd;
            bestj = g0 ? (u32)(2*j) : bestj;
            bool g1 = d1 > bestd;
            bestd = g1 ? d1 : bestd;
            bestj = g1 ? (u32)(2*j+1) : bestj;
        }
        // dist >= 0 so float bits are order-monotone
        u32 hi = __float_as_uint(bestd);
        u32 lo = (u32)(NP - 1 - (t * 16 + (int)bestj));   // larger = smaller idx
        u32 mh = wave_max_u32(hi);
        u32 cl = (hi == mh) ? lo : 0u;
        u32 ml = wave_max_u32(cl);
        if (lane == 0) wavekey[g & 1][wid] = ((u64)mh << 32) | (u64)ml;
        __syncthreads();

        u64 wk = wavekey[g & 1][0];
        #pragma unroll
        for (int w = 1; w < 8; ++w) {
            u64 o = wavekey[g & 1][w];
            wk = (o > wk) ? o : wk;
        }
        const int widx = NP - 1 - (int)(u32)(wk & 0xFFFFFFFFull);
        // broadcast fetch of the new centroid (same address in all lanes; L2-hot)
        const float* cp = base + (size_t)widx * 3;
        cx = cp[0]; cy = cp[1]; cz = cp[2];
        if (t == 0) {
            float* o = out + ((size_t)b * NG + g + 1) * 3;
            o[0] = cx; o[1] = cy; o[2] = cz;
        }
    }
}

// ---------------------------------------------------------------------------
// Kernel 2: 32-NN mean per (batch, center). One WAVE per task. Stream the
// batch in 32 chunks of 256 points, staged LINEARLY into per-wave double-
// buffered LDS with fully-coalesced loads; each lane reads 4 points
// (stride-64 interleave) per chunk from LDS (bank (3*lane+j)%32 bijective
// per 32 lanes -> 2-way conflict = free). No barriers: per-wave LDS region,
// same-wave DS ops are in-order.
// Extraction: DPP min over dist bits, then DPP min over tied indices.
// REFILL IS WAVE-COLLECTIVE (round-6 bug fix): the scan stages LDS, so it
// must run under full exec. When any lane empties, ALL lanes rescan with
// their own filter (pk > L_lane; L==0 <=> lane never extracted, since a
// packed key is never 0 for non-NaN dists). A lane's extracted keys are
// exactly its candidates <= its own L, so the filtered rescan reproduces
// its current unextracted state and replenishes to 4 valid entries
// (>=96 of its 128 candidates always remain).
// ---------------------------------------------------------------------------
__device__ __forceinline__ void insert4(u64 pk, u64& t0, u64& t1, u64& t2, u64& t3) {
    if (pk < t3) {
        t3 = pk;
        if (t3 < t2) { u64 tmp = t2; t2 = t3; t3 = tmp; }
        if (t2 < t1) { u64 tmp = t1; t1 = t2; t2 = tmp; }
        if (t1 < t0) { u64 tmp = t0; t0 = t1; t1 = tmp; }
    }
}

__device__ __forceinline__ void scan_top4(const float4* __restrict__ gsrc,
                                          float* __restrict__ buf0,
                                          float* __restrict__ buf1,
                                          float cx, float cy, float cz, float s2,
                                          u64 L, bool useL, int lane,
                                          u64& t0, u64& t1, u64& t2, u64& t3)
{
    #pragma clang fp contract(off)
    t0 = t1 = t2 = t3 = ~0ull;

    // prologue: chunk 0 -> buf0; chunk 1 -> regs
    {
        float4 a0 = gsrc[lane], a1 = gsrc[64 + lane], a2 = gsrc[128 + lane];
        float4* w0 = reinterpret_cast<float4*>(buf0);
        w0[lane] = a0; w0[64 + lane] = a1; w0[128 + lane] = a2;
    }
    float4 r0 = gsrc[192 + lane], r1 = gsrc[256 + lane], r2 = gsrc[320 + lane];

    for (int c = 0; c < 32; ++c) {
        float* cur = (c & 1) ? buf1 : buf0;
        float* nxt = (c & 1) ? buf0 : buf1;
        if (c < 31) {
            float4* wn = reinterpret_cast<float4*>(nxt);
            wn[lane] = r0; wn[64 + lane] = r1; wn[128 + lane] = r2;
        }
        if (c < 30) {
            const float4* gn = gsrc + (size_t)(c + 2) * 192;
            r0 = gn[lane]; r1 = gn[64 + lane]; r2 = gn[128 + lane];
        }
        #pragma unroll
        for (int k = 0; k < 4; ++k) {
            const int p = k * 64 + lane;
            const float* q = cur + 3 * p;
            float nx = q[0], ny = q[1], nz = q[2];
            // reference: (||s||^2 - 2*(s.n)) + ||n||^2, left-to-right, no FMA
            float dotv = __fadd_rn(__fadd_rn(__fmul_rn(cx,nx), __fmul_rn(cy,ny)), __fmul_rn(cz,nz));
            float n2   = dist3(nx, ny, nz);
            float d    = __fadd_rn(__fsub_rn(s2, __fmul_rn(2.0f, dotv)), n2);
            // monotone map f32 -> u32 (handles the tiny-negative self-distance)
            u32 u  = __float_as_uint(d);
            u32 kk = u ^ (u32)(((int)u >> 31) | 0x80000000);
            int idx = c * 256 + p;
            u64 pk = ((u64)kk << 32) | (u64)(u32)idx;
            if (!useL || pk > L) insert4(pk, t0, t1, t2, t3);
        }
    }
}

__global__ __launch_bounds__(256) void knn_kernel(const float* __restrict__ xyz,
                                                  float* __restrict__ out)
{
    __shared__ float ldsbuf[4][2][768];   // 24 KiB: per-wave double buffer

    const int t    = threadIdx.x;
    const int lane = t & 63;
    const int wid  = t >> 6;
    const int task = blockIdx.x * 4 + wid;   // 0..8191
    const int b    = task >> 8;
    const int g    = task & 255;

    const float* cptr = out + ((size_t)b * NG + g) * 3;   // centers from fps_kernel
    const float cx = cptr[0], cy = cptr[1], cz = cptr[2];
    const float s2 = dist3(cx, cy, cz);

    const float4* gsrc = reinterpret_cast<const float4*>(xyz + (size_t)b * NP * 3);
    float* buf0 = &ldsbuf[wid][0][0];
    float* buf1 = &ldsbuf[wid][1][0];

    u64 t0, t1, t2, t3;
    scan_top4(gsrc, buf0, buf1, cx, cy, cz, s2, 0ull, false, lane, t0, t1, t2, t3);
    int cnt = 4;
    u64 L = 0;
    u32 myWin = 0;

    for (int round = 0; round < NK; ++round) {
        if (__ballot(cnt == 0) != 0ull) {
            // wave-collective refill (full exec for the LDS staging); per-lane
            // filter pk > L reproduces each lane's unextracted state exactly.
            scan_top4(gsrc, buf0, buf1, cx, cy, cz, s2, L, L != 0ull, lane, t0, t1, t2, t3);
            cnt = 4;
        }
        u32 hi0 = (u32)(t0 >> 32);
        u32 lo0 = (u32)(t0 & 0xFFFFFFFFull);
        u32 mh = wave_min_u32(hi0);
        u32 cl = (hi0 == mh) ? lo0 : 0xFFFFFFFFu;
        u32 ml = wave_min_u32(cl);            // smallest tied index (matches top_k order)
        u64 w  = ((u64)mh << 32) | (u64)ml;
        if (t0 == w) {                        // unique owner (idx packed in key)
            L = w;
            t0 = t1; t1 = t2; t2 = t3; t3 = ~0ull;
            --cnt;
        }
        if (lane == round) myWin = ml;
    }

    float sx = 0.f, sy = 0.f, sz = 0.f;
    if (lane < NK) {
        const float* p = xyz + ((size_t)b * NP + myWin) * 3;
        sx = p[0]; sy = p[1]; sz = p[2];
    }
    #pragma unroll
    for (int m = 32; m >= 1; m >>= 1) {
        sx += __shfl_xor(sx, m, 64);
        sy += __shfl_xor(sy, m, 64);
        sz += __shfl_xor(sz, m, 64);
    }
    if (lane == 0) {
        float* o = out + (size_t)NB * NG * 3 + ((size_t)b * NG + g) * 3;
        const float inv = 1.0f / 32.0f;   // /32 exact (power of 2)
        o[0] = sx * inv; o[1] = sy * inv; o[2] = sz * inv;
    }
}

extern "C" void kernel_launch(void* const* d_in, const int* in_sizes, int n_in,
                              void* d_out, int out_size, void* d_ws, size_t ws_size,
                              hipStream_t stream)
{
    const float* xyz = (const float*)d_in[0];
    float* out = (float*)d_out;

    hipLaunchKernelGGL(fps_kernel, dim3(NB), dim3(512), 0, stream, xyz, out);

    const int tasks  = NB * NG;            // 8192
    const int blocks = tasks / 4;          // 4 waves (tasks) per 256-thread block
    hipLaunchKernelGGL(knn_kernel, dim3(blocks), dim3(256), 0, stream, xyz, out);
}